// Round 1
// 365.555 us; speedup vs baseline: 1.0847x; 1.0847x over previous
//
#include <hip/hip_runtime.h>

#define N_NODES 100000
#define N_EDGES 1600000
#define IN_CH 256
#define HID_CH 128
#define SCAN_BLOCKS ((N_NODES + 255) / 256)   // 391

typedef __attribute__((ext_vector_type(8))) short short8;
typedef __attribute__((ext_vector_type(4))) float floatx4;

// fp32 -> bf16 round-to-nearest-even (scalar path, epilogue of small kernels)
static __device__ __forceinline__ unsigned short f2bf(float f) {
    unsigned int u = __float_as_uint(f);
    u += 0x7fffu + ((u >> 16) & 1u);
    return (unsigned short)(u >> 16);
}

// packed fp32x2 -> bf16x2 (RNE), S0 -> low16, S1 -> high16
static __device__ __forceinline__ unsigned cvt_pk_bf16(float lo, float hi) {
    unsigned r;
    asm("v_cvt_pk_bf16_f32 %0, %1, %2" : "=v"(r) : "v"(lo), "v"(hi));
    return r;
}

// ---------------- CSR build ----------------

// counts + per-edge rank in one pass
__global__ void count_kernel(const int* __restrict__ dst, int* __restrict__ counts,
                             int* __restrict__ rank) {
    int e = blockIdx.x * blockDim.x + threadIdx.x;
    if (e < N_EDGES) rank[e] = atomicAdd(&counts[dst[e]], 1);
}

__global__ void scanA_kernel(const int* __restrict__ counts, int* __restrict__ row_start,
                             int* __restrict__ partials) {
    __shared__ int ss[256];
    int tid = threadIdx.x;
    int i = blockIdx.x * 256 + tid;
    int v = (i < N_NODES) ? counts[i] : 0;
    ss[tid] = v;
    __syncthreads();
    for (int off = 1; off < 256; off <<= 1) {
        int t = (tid >= off) ? ss[tid - off] : 0;
        __syncthreads();
        ss[tid] += t;
        __syncthreads();
    }
    if (i < N_NODES) row_start[i] = ss[tid] - v;
    if (tid == 255) partials[blockIdx.x] = ss[255];
}

__global__ void scanB_kernel(int* __restrict__ partials) {
    __shared__ int ss[512];
    int tid = threadIdx.x;
    int v = (tid < SCAN_BLOCKS) ? partials[tid] : 0;
    ss[tid] = v;
    __syncthreads();
    for (int off = 1; off < 512; off <<= 1) {
        int t = (tid >= off) ? ss[tid - off] : 0;
        __syncthreads();
        ss[tid] += t;
        __syncthreads();
    }
    if (tid < SCAN_BLOCKS) partials[tid] = ss[tid] - v;
}

__global__ void scanC_kernel(int* __restrict__ row_start, const int* __restrict__ partials,
                             const int* __restrict__ counts, float* __restrict__ dinv) {
    int i = blockIdx.x * 256 + threadIdx.x;
    if (i >= N_NODES) return;
    row_start[i] += partials[blockIdx.x];
    dinv[i] = rsqrtf((float)(counts[i] + 1));   // +1 self loop
    if (i == 0) row_start[N_NODES] = N_EDGES;
}

// atomic-free reorder: pos known from rank
__global__ void reorder_kernel(const int* __restrict__ ei, const int* __restrict__ rank,
                               const int* __restrict__ row_start, int* __restrict__ sorted) {
    int e = blockIdx.x * blockDim.x + threadIdx.x;
    if (e >= N_EDGES) return;
    int dst = ei[N_EDGES + e];
    sorted[row_start[dst] + rank[e]] = ei[e];
}

// ---------------- W^T -> bf16 (one-time, 32K elems) ----------------

__global__ void wt_kernel(const float* __restrict__ W, unsigned short* __restrict__ Wt) {
    int i = blockIdx.x * blockDim.x + threadIdx.x;   // over IN_CH*HID_CH
    if (i >= IN_CH * HID_CH) return;
    int k = i >> 7;          // IN index
    int c = i & 127;         // HID index
    Wt[c * IN_CH + k] = f2bf(W[i]);
}

// ---------------- MFMA GEMM: hp = bf16( dinv[row] * (x @ W) ) ----------------
// 512 threads = 8 waves per block; block covers 256 rows (32 rows/wave).
// Wt staged once per block into LDS (64 KB, XOR-swizzled to kill the
// stride-512B bank conflict on ds_read_b128). A comes straight from global
// fp32 x with an explicit 2-deep register double-buffer so the next K-step's
// loads are in flight while the current one computes.

__launch_bounds__(512)
__global__ void gemm_mfma_kernel(const float* __restrict__ x,
                                 const unsigned short* __restrict__ Wt,
                                 const float* __restrict__ dinv,
                                 unsigned short* __restrict__ hp) {
    __shared__ unsigned short Bs[IN_CH * HID_CH];   // 64 KB, swizzled

    int tid = threadIdx.x;

    // ---- stage Wt -> LDS, swizzled: byte ^= ((col&7)<<4) ----
    {
        const uint4* src = (const uint4*)Wt;
#pragma unroll
        for (int i = 0; i < 8; ++i) {
            int j = i * 512 + tid;                   // 16B chunk index, 4096 total
            unsigned lb = (unsigned)j * 16u;         // linear byte offset
            unsigned c7 = (lb >> 9) & 7u;            // col & 7 (row stride = 512B)
            unsigned db = lb ^ (c7 << 4);
            *(uint4*)((char*)Bs + db) = src[j];
        }
    }
    __syncthreads();

    int wave = tid >> 6;
    int lane = tid & 63;
    int row0 = blockIdx.x * 256 + wave * 32;
    if (row0 >= N_NODES) return;      // no barriers after this point

    int m = lane & 15;
    int q = lane >> 4;

    floatx4 acc[2][8];
#pragma unroll
    for (int i = 0; i < 2; ++i)
#pragma unroll
        for (int t = 0; t < 8; ++t) acc[i][t] = (floatx4){0.f, 0.f, 0.f, 0.f};

    // per-lane A base pointers: tile0 row = row0+m, tile1 row = row0+16+m
    const float* xp0 = &x[(size_t)(row0 + m) * IN_CH + q * 8];
    const float* xp1 = xp0 + 16 * IN_CH;

    float4 aA[4], aB[4];

#define LOADA(buf, kstep)                                          \
    do {                                                           \
        const float* p0_ = xp0 + (kstep) * 32;                     \
        const float* p1_ = xp1 + (kstep) * 32;                     \
        buf[0] = *(const float4*)(p0_);                            \
        buf[1] = *(const float4*)(p0_ + 4);                        \
        buf[2] = *(const float4*)(p1_);                            \
        buf[3] = *(const float4*)(p1_ + 4);                        \
    } while (0)

#define COMPUTE(buf, kstep)                                                     \
    do {                                                                        \
        union { short8 v; unsigned u[4]; } af0_, af1_;                          \
        af0_.u[0] = cvt_pk_bf16(buf[0].x, buf[0].y);                            \
        af0_.u[1] = cvt_pk_bf16(buf[0].z, buf[0].w);                            \
        af0_.u[2] = cvt_pk_bf16(buf[1].x, buf[1].y);                            \
        af0_.u[3] = cvt_pk_bf16(buf[1].z, buf[1].w);                            \
        af1_.u[0] = cvt_pk_bf16(buf[2].x, buf[2].y);                            \
        af1_.u[1] = cvt_pk_bf16(buf[2].z, buf[2].w);                            \
        af1_.u[2] = cvt_pk_bf16(buf[3].x, buf[3].y);                            \
        af1_.u[3] = cvt_pk_bf16(buf[3].z, buf[3].w);                            \
        int kb_ = ((kstep) * 32 + q * 8) * 2;                                   \
        _Pragma("unroll")                                                       \
        for (int t = 0; t < 8; ++t) {                                           \
            int c_ = t * 16 + m;                                                \
            unsigned db_ = (unsigned)(c_ * 512 + kb_) ^ ((unsigned)(c_ & 7) << 4); \
            short8 bf_ = *(const short8*)((const char*)Bs + db_);               \
            acc[0][t] = __builtin_amdgcn_mfma_f32_16x16x32_bf16(af0_.v, bf_, acc[0][t], 0, 0, 0); \
            acc[1][t] = __builtin_amdgcn_mfma_f32_16x16x32_bf16(af1_.v, bf_, acc[1][t], 0, 0, 0); \
        }                                                                       \
    } while (0)

    LOADA(aA, 0);
#pragma unroll 1
    for (int ks = 0; ks < 8; ks += 2) {
        LOADA(aB, ks + 1);
        COMPUTE(aA, ks);
        if (ks < 6) LOADA(aA, ks + 2);
        COMPUTE(aB, ks + 1);
    }

#undef LOADA
#undef COMPUTE

    // C/D layout: col = lane&15 (=m), row = q*4 + reg (within each 16-row tile)
#pragma unroll
    for (int tile = 0; tile < 2; ++tile) {
#pragma unroll
        for (int reg = 0; reg < 4; ++reg) {
            int grow = row0 + tile * 16 + q * 4 + reg;
            float di = dinv[grow];
            unsigned short* op = &hp[(size_t)grow * HID_CH + m];
#pragma unroll
            for (int tp = 0; tp < 4; ++tp) {
                unsigned d = cvt_pk_bf16(acc[tile][2 * tp][reg] * di,
                                         acc[tile][2 * tp + 1][reg] * di);
                op[(2 * tp) * 16]     = (unsigned short)(d & 0xffffu);
                op[(2 * tp + 1) * 16] = (unsigned short)(d >> 16);
            }
        }
    }
}

// ---------------- gather + finalize ----------------
// One wave per node, 4 edges in flight (16 lanes x 8 channels x 16B each).

__launch_bounds__(256)
__global__ void gather_finalize_kernel(const int* __restrict__ row_start,
                                       const int* __restrict__ sorted,
                                       const float* __restrict__ dinv,
                                       const unsigned short* __restrict__ hp,
                                       const float* __restrict__ bias,
                                       const float* __restrict__ alpha,
                                       float* __restrict__ out) {
    int node = (blockIdx.x * blockDim.x + threadIdx.x) >> 6;
    int lane = threadIdx.x & 63;
    if (node >= N_NODES) return;

    int beg = row_start[node];
    int end = row_start[node + 1];
    int part = lane >> 4;          // 0..3: which edge of the group of 4
    int ch = (lane & 15) * 8;      // 8 channels per lane

    float acc[8];
#pragma unroll
    for (int i = 0; i < 8; ++i) acc[i] = 0.f;

    for (int k = beg + part; k < end; k += 4) {
        int s = sorted[k];
        uint4 u = *(const uint4*)&hp[(size_t)s * HID_CH + ch];
        acc[0] += __uint_as_float(u.x << 16);
        acc[1] += __uint_as_float(u.x & 0xffff0000u);
        acc[2] += __uint_as_float(u.y << 16);
        acc[3] += __uint_as_float(u.y & 0xffff0000u);
        acc[4] += __uint_as_float(u.z << 16);
        acc[5] += __uint_as_float(u.z & 0xffff0000u);
        acc[6] += __uint_as_float(u.w << 16);
        acc[7] += __uint_as_float(u.w & 0xffff0000u);
    }

    // combine the 4 edge-parts (lanes 0-15 / 16-31 / 32-47 / 48-63)
#pragma unroll
    for (int i = 0; i < 8; ++i) {
        acc[i] += __shfl_xor(acc[i], 16);
        acc[i] += __shfl_xor(acc[i], 32);
    }

    if (part == 0) {
        float di = dinv[node];
        uint4 us = *(const uint4*)&hp[(size_t)node * HID_CH + ch];
        float sf[8];
        sf[0] = __uint_as_float(us.x << 16);
        sf[1] = __uint_as_float(us.x & 0xffff0000u);
        sf[2] = __uint_as_float(us.y << 16);
        sf[3] = __uint_as_float(us.y & 0xffff0000u);
        sf[4] = __uint_as_float(us.z << 16);
        sf[5] = __uint_as_float(us.z & 0xffff0000u);
        sf[6] = __uint_as_float(us.w << 16);
        sf[7] = __uint_as_float(us.w & 0xffff0000u);

        float4 b0 = *(const float4*)&bias[ch];
        float4 b1 = *(const float4*)&bias[ch + 4];
        float4 a0 = *(const float4*)&alpha[ch];
        float4 a1 = *(const float4*)&alpha[ch + 4];
        float bv[8] = {b0.x, b0.y, b0.z, b0.w, b1.x, b1.y, b1.z, b1.w};
        float av[8] = {a0.x, a0.y, a0.z, a0.w, a1.x, a1.y, a1.z, a1.w};

        float r[8];
#pragma unroll
        for (int i = 0; i < 8; ++i) {
            float v = di * (acc[i] + sf[i]) + bv[i];
            r[i] = v > 0.f ? v : av[i] * v;
        }
        float4 o0 = make_float4(r[0], r[1], r[2], r[3]);
        float4 o1 = make_float4(r[4], r[5], r[6], r[7]);
        *(float4*)&out[(size_t)node * HID_CH + ch] = o0;
        *(float4*)&out[(size_t)node * HID_CH + ch + 4] = o1;
    }
}

// ---------------- launch ----------------

extern "C" void kernel_launch(void* const* d_in, const int* in_sizes, int n_in,
                              void* d_out, int out_size, void* d_ws, size_t ws_size,
                              hipStream_t stream) {
    const float* x     = (const float*)d_in[0];
    const int*   ei    = (const int*)d_in[1];     // [2, E]: [0..E)=src, [E..2E)=dst
    const float* W     = (const float*)d_in[2];
    const float* bias  = (const float*)d_in[3];
    const float* alpha = (const float*)d_in[4];
    float* out = (float*)d_out;

    char* p = (char*)d_ws;
    auto align512 = [](size_t v) { return (v + 511) / 512 * 512; };
    unsigned short* hp = (unsigned short*)p; p += align512((size_t)N_NODES * HID_CH * 2);
    unsigned short* Wt = (unsigned short*)p; p += align512((size_t)IN_CH * HID_CH * 2);
    int* counts    = (int*)p;   p += align512((size_t)N_NODES * 4);
    float* dinv    = (float*)p; p += align512((size_t)N_NODES * 4);
    int* row_start = (int*)p;   p += align512((size_t)(N_NODES + 1) * 4);
    int* rank      = (int*)p;   p += align512((size_t)N_EDGES * 4);
    int* partials  = (int*)p;   p += align512(512 * 4);
    int* sorted    = (int*)p;   p += align512((size_t)N_EDGES * 4);

    hipMemsetAsync(counts, 0, (size_t)N_NODES * sizeof(int), stream);

    count_kernel<<<(N_EDGES + 255) / 256, 256, 0, stream>>>(ei + N_EDGES, counts, rank);
    scanA_kernel<<<SCAN_BLOCKS, 256, 0, stream>>>(counts, row_start, partials);
    scanB_kernel<<<1, 512, 0, stream>>>(partials);
    scanC_kernel<<<SCAN_BLOCKS, 256, 0, stream>>>(row_start, partials, counts, dinv);
    reorder_kernel<<<(N_EDGES + 255) / 256, 256, 0, stream>>>(ei, rank, row_start, sorted);

    wt_kernel<<<(IN_CH * HID_CH + 255) / 256, 256, 0, stream>>>(W, Wt);

    // 512 threads/block, 256 rows/block
    gemm_mfma_kernel<<<(N_NODES + 255) / 256, 512, 0, stream>>>(x, Wt, dinv, hp);

    long long gthreads = (long long)N_NODES * 64;
    gather_finalize_kernel<<<(int)((gthreads + 255) / 256), 256, 0, stream>>>(
        row_start, sorted, dinv, hp, bias, alpha, out);
}

// Round 2
// 356.539 us; speedup vs baseline: 1.1122x; 1.0253x over previous
//
#include <hip/hip_runtime.h>

#define N_NODES 100000
#define N_EDGES 1600000
#define IN_CH 256
#define HID_CH 128
#define SCAN_BLOCKS ((N_NODES + 255) / 256)   // 391

typedef __attribute__((ext_vector_type(8))) short short8;
typedef __attribute__((ext_vector_type(4))) float floatx4;

// fp32 -> bf16 round-to-nearest-even (scalar path, epilogue of small kernels)
static __device__ __forceinline__ unsigned short f2bf(float f) {
    unsigned int u = __float_as_uint(f);
    u += 0x7fffu + ((u >> 16) & 1u);
    return (unsigned short)(u >> 16);
}

// packed fp32x2 -> bf16x2 (RNE), S0 -> low16, S1 -> high16
static __device__ __forceinline__ unsigned cvt_pk_bf16(float lo, float hi) {
    unsigned r;
    asm("v_cvt_pk_bf16_f32 %0, %1, %2" : "=v"(r) : "v"(lo), "v"(hi));
    return r;
}

// ---------------- CSR build ----------------

// counts + per-edge rank in one pass
__global__ void count_kernel(const int* __restrict__ dst, int* __restrict__ counts,
                             int* __restrict__ rank) {
    int e = blockIdx.x * blockDim.x + threadIdx.x;
    if (e < N_EDGES) rank[e] = atomicAdd(&counts[dst[e]], 1);
}

__global__ void scanA_kernel(const int* __restrict__ counts, int* __restrict__ row_start,
                             int* __restrict__ partials) {
    __shared__ int ss[256];
    int tid = threadIdx.x;
    int i = blockIdx.x * 256 + tid;
    int v = (i < N_NODES) ? counts[i] : 0;
    ss[tid] = v;
    __syncthreads();
    for (int off = 1; off < 256; off <<= 1) {
        int t = (tid >= off) ? ss[tid - off] : 0;
        __syncthreads();
        ss[tid] += t;
        __syncthreads();
    }
    if (i < N_NODES) row_start[i] = ss[tid] - v;
    if (tid == 255) partials[blockIdx.x] = ss[255];
}

__global__ void scanB_kernel(int* __restrict__ partials) {
    __shared__ int ss[512];
    int tid = threadIdx.x;
    int v = (tid < SCAN_BLOCKS) ? partials[tid] : 0;
    ss[tid] = v;
    __syncthreads();
    for (int off = 1; off < 512; off <<= 1) {
        int t = (tid >= off) ? ss[tid - off] : 0;
        __syncthreads();
        ss[tid] += t;
        __syncthreads();
    }
    if (tid < SCAN_BLOCKS) partials[tid] = ss[tid] - v;
}

__global__ void scanC_kernel(int* __restrict__ row_start, const int* __restrict__ partials,
                             const int* __restrict__ counts, float* __restrict__ dinv) {
    int i = blockIdx.x * 256 + threadIdx.x;
    if (i >= N_NODES) return;
    row_start[i] += partials[blockIdx.x];
    dinv[i] = rsqrtf((float)(counts[i] + 1));   // +1 self loop
    if (i == 0) row_start[N_NODES] = N_EDGES;
}

// atomic-free reorder: pos known from rank
__global__ void reorder_kernel(const int* __restrict__ ei, const int* __restrict__ rank,
                               const int* __restrict__ row_start, int* __restrict__ sorted) {
    int e = blockIdx.x * blockDim.x + threadIdx.x;
    if (e >= N_EDGES) return;
    int dst = ei[N_EDGES + e];
    sorted[row_start[dst] + rank[e]] = ei[e];
}

// ---------------- W^T -> bf16 (one-time, 32K elems) ----------------

__global__ void wt_kernel(const float* __restrict__ W, unsigned short* __restrict__ Wt) {
    int i = blockIdx.x * blockDim.x + threadIdx.x;   // over IN_CH*HID_CH
    if (i >= IN_CH * HID_CH) return;
    int k = i >> 7;          // IN index
    int c = i & 127;         // HID index
    Wt[c * IN_CH + k] = f2bf(W[i]);
}

// ---------------- MFMA GEMM: hp = bf16( dinv[row] * (x @ W) ) ----------------
// 512 threads = 8 waves per block; block covers 256 rows (32 rows/wave).
// Wt staged once per block into LDS (64 KB, XOR-swizzled). A from global fp32 x
// with an explicit 2-deep register double-buffer.

__launch_bounds__(512)
__global__ void gemm_mfma_kernel(const float* __restrict__ x,
                                 const unsigned short* __restrict__ Wt,
                                 const float* __restrict__ dinv,
                                 unsigned short* __restrict__ hp) {
    __shared__ unsigned short Bs[IN_CH * HID_CH];   // 64 KB, swizzled

    int tid = threadIdx.x;

    // ---- stage Wt -> LDS, swizzled: byte ^= ((col&7)<<4) ----
    {
        const uint4* src = (const uint4*)Wt;
#pragma unroll
        for (int i = 0; i < 8; ++i) {
            int j = i * 512 + tid;                   // 16B chunk index, 4096 total
            unsigned lb = (unsigned)j * 16u;         // linear byte offset
            unsigned c7 = (lb >> 9) & 7u;            // col & 7 (row stride = 512B)
            unsigned db = lb ^ (c7 << 4);
            *(uint4*)((char*)Bs + db) = src[j];
        }
    }
    __syncthreads();

    int wave = tid >> 6;
    int lane = tid & 63;
    int row0 = blockIdx.x * 256 + wave * 32;
    if (row0 >= N_NODES) return;      // no barriers after this point

    int m = lane & 15;
    int q = lane >> 4;

    floatx4 acc[2][8];
#pragma unroll
    for (int i = 0; i < 2; ++i)
#pragma unroll
        for (int t = 0; t < 8; ++t) acc[i][t] = (floatx4){0.f, 0.f, 0.f, 0.f};

    // per-lane A base pointers: tile0 row = row0+m, tile1 row = row0+16+m
    const float* xp0 = &x[(size_t)(row0 + m) * IN_CH + q * 8];
    const float* xp1 = xp0 + 16 * IN_CH;

    float4 aA[4], aB[4];

#define LOADA(buf, kstep)                                          \
    do {                                                           \
        const float* p0_ = xp0 + (kstep) * 32;                     \
        const float* p1_ = xp1 + (kstep) * 32;                     \
        buf[0] = *(const float4*)(p0_);                            \
        buf[1] = *(const float4*)(p0_ + 4);                        \
        buf[2] = *(const float4*)(p1_);                            \
        buf[3] = *(const float4*)(p1_ + 4);                        \
    } while (0)

#define COMPUTE(buf, kstep)                                                     \
    do {                                                                        \
        union { short8 v; unsigned u[4]; } af0_, af1_;                          \
        af0_.u[0] = cvt_pk_bf16(buf[0].x, buf[0].y);                            \
        af0_.u[1] = cvt_pk_bf16(buf[0].z, buf[0].w);                            \
        af0_.u[2] = cvt_pk_bf16(buf[1].x, buf[1].y);                            \
        af0_.u[3] = cvt_pk_bf16(buf[1].z, buf[1].w);                            \
        af1_.u[0] = cvt_pk_bf16(buf[2].x, buf[2].y);                            \
        af1_.u[1] = cvt_pk_bf16(buf[2].z, buf[2].w);                            \
        af1_.u[2] = cvt_pk_bf16(buf[3].x, buf[3].y);                            \
        af1_.u[3] = cvt_pk_bf16(buf[3].z, buf[3].w);                            \
        int kb_ = ((kstep) * 32 + q * 8) * 2;                                   \
        _Pragma("unroll")                                                       \
        for (int t = 0; t < 8; ++t) {                                           \
            int c_ = t * 16 + m;                                                \
            unsigned db_ = (unsigned)(c_ * 512 + kb_) ^ ((unsigned)(c_ & 7) << 4); \
            short8 bf_ = *(const short8*)((const char*)Bs + db_);               \
            acc[0][t] = __builtin_amdgcn_mfma_f32_16x16x32_bf16(af0_.v, bf_, acc[0][t], 0, 0, 0); \
            acc[1][t] = __builtin_amdgcn_mfma_f32_16x16x32_bf16(af1_.v, bf_, acc[1][t], 0, 0, 0); \
        }                                                                       \
    } while (0)

    LOADA(aA, 0);
#pragma unroll 1
    for (int ks = 0; ks < 8; ks += 2) {
        LOADA(aB, ks + 1);
        COMPUTE(aA, ks);
        if (ks < 6) LOADA(aA, ks + 2);
        COMPUTE(aB, ks + 1);
    }

#undef LOADA
#undef COMPUTE

    // C/D layout: col = lane&15 (=m), row = q*4 + reg (within each 16-row tile)
#pragma unroll
    for (int tile = 0; tile < 2; ++tile) {
#pragma unroll
        for (int reg = 0; reg < 4; ++reg) {
            int grow = row0 + tile * 16 + q * 4 + reg;
            float di = dinv[grow];
            unsigned short* op = &hp[(size_t)grow * HID_CH + m];
#pragma unroll
            for (int tp = 0; tp < 4; ++tp) {
                unsigned d = cvt_pk_bf16(acc[tile][2 * tp][reg] * di,
                                         acc[tile][2 * tp + 1][reg] * di);
                op[(2 * tp) * 16]     = (unsigned short)(d & 0xffffu);
                op[(2 * tp + 1) * 16] = (unsigned short)(d >> 16);
            }
        }
    }
}

// ---------------- gather + finalize ----------------
// One wave per node, 4 edge-chains (parts) x 16 lanes x 8ch (uint4).
// Edge loop unrolled 4x per part with branchless masking: 16 independent
// hp-row loads in flight per wave; the average node (deg 16) completes its
// whole aggregation in ONE idx-latency + ONE data-latency.

static __device__ __forceinline__ void acc_bf16x8(float* acc, uint4 u, float w) {
    acc[0] += w * __uint_as_float(u.x << 16);
    acc[1] += w * __uint_as_float(u.x & 0xffff0000u);
    acc[2] += w * __uint_as_float(u.y << 16);
    acc[3] += w * __uint_as_float(u.y & 0xffff0000u);
    acc[4] += w * __uint_as_float(u.z << 16);
    acc[5] += w * __uint_as_float(u.z & 0xffff0000u);
    acc[6] += w * __uint_as_float(u.w << 16);
    acc[7] += w * __uint_as_float(u.w & 0xffff0000u);
}

__launch_bounds__(256)
__global__ void gather_finalize_kernel(const int* __restrict__ row_start,
                                       const int* __restrict__ sorted,
                                       const float* __restrict__ dinv,
                                       const unsigned short* __restrict__ hp,
                                       const float* __restrict__ bias,
                                       const float* __restrict__ alpha,
                                       float* __restrict__ out) {
    int node = (blockIdx.x * blockDim.x + threadIdx.x) >> 6;
    int lane = threadIdx.x & 63;
    if (node >= N_NODES) return;

    int beg = row_start[node];
    int end = row_start[node + 1];
    int part = lane >> 4;          // 0..3: which edge-chain
    int ch = (lane & 15) * 8;      // 8 channels per lane

    // independent loads issued before the edge loop (overlap its latency)
    float di = dinv[node];
    uint4 us = *(const uint4*)&hp[(size_t)node * HID_CH + ch];

    float acc[8];
#pragma unroll
    for (int i = 0; i < 8; ++i) acc[i] = 0.f;

    // 4x-unrolled masked edge loop: this part's edges are beg+part, +4, +8, ...
    for (int k = beg + part; k < end; k += 16) {
        int k1 = k + 4, k2 = k + 8, k3 = k + 12;
        int e1 = end - 1;
        int s0 = sorted[k];
        int s1 = sorted[k1 < end ? k1 : e1];
        int s2 = sorted[k2 < end ? k2 : e1];
        int s3 = sorted[k3 < end ? k3 : e1];
        uint4 u0 = *(const uint4*)&hp[(size_t)s0 * HID_CH + ch];
        uint4 u1 = *(const uint4*)&hp[(size_t)s1 * HID_CH + ch];
        uint4 u2 = *(const uint4*)&hp[(size_t)s2 * HID_CH + ch];
        uint4 u3 = *(const uint4*)&hp[(size_t)s3 * HID_CH + ch];
        float w1 = k1 < end ? 1.f : 0.f;
        float w2 = k2 < end ? 1.f : 0.f;
        float w3 = k3 < end ? 1.f : 0.f;
        acc_bf16x8(acc, u0, 1.f);
        acc_bf16x8(acc, u1, w1);
        acc_bf16x8(acc, u2, w2);
        acc_bf16x8(acc, u3, w3);
    }

    // combine the 4 edge-parts (lanes 0-15 / 16-31 / 32-47 / 48-63)
#pragma unroll
    for (int i = 0; i < 8; ++i) {
        acc[i] += __shfl_xor(acc[i], 16);
        acc[i] += __shfl_xor(acc[i], 32);
    }

    if (part == 0) {
        float sf[8];
        sf[0] = __uint_as_float(us.x << 16);
        sf[1] = __uint_as_float(us.x & 0xffff0000u);
        sf[2] = __uint_as_float(us.y << 16);
        sf[3] = __uint_as_float(us.y & 0xffff0000u);
        sf[4] = __uint_as_float(us.z << 16);
        sf[5] = __uint_as_float(us.z & 0xffff0000u);
        sf[6] = __uint_as_float(us.w << 16);
        sf[7] = __uint_as_float(us.w & 0xffff0000u);

        float4 b0 = *(const float4*)&bias[ch];
        float4 b1 = *(const float4*)&bias[ch + 4];
        float4 a0 = *(const float4*)&alpha[ch];
        float4 a1 = *(const float4*)&alpha[ch + 4];
        float bv[8] = {b0.x, b0.y, b0.z, b0.w, b1.x, b1.y, b1.z, b1.w};
        float av[8] = {a0.x, a0.y, a0.z, a0.w, a1.x, a1.y, a1.z, a1.w};

        float r[8];
#pragma unroll
        for (int i = 0; i < 8; ++i) {
            float v = di * (acc[i] + sf[i]) + bv[i];
            r[i] = v > 0.f ? v : av[i] * v;
        }
        float4 o0 = make_float4(r[0], r[1], r[2], r[3]);
        float4 o1 = make_float4(r[4], r[5], r[6], r[7]);
        *(float4*)&out[(size_t)node * HID_CH + ch] = o0;
        *(float4*)&out[(size_t)node * HID_CH + ch + 4] = o1;
    }
}

// ---------------- launch ----------------

extern "C" void kernel_launch(void* const* d_in, const int* in_sizes, int n_in,
                              void* d_out, int out_size, void* d_ws, size_t ws_size,
                              hipStream_t stream) {
    const float* x     = (const float*)d_in[0];
    const int*   ei    = (const int*)d_in[1];     // [2, E]: [0..E)=src, [E..2E)=dst
    const float* W     = (const float*)d_in[2];
    const float* bias  = (const float*)d_in[3];
    const float* alpha = (const float*)d_in[4];
    float* out = (float*)d_out;

    char* p = (char*)d_ws;
    auto align512 = [](size_t v) { return (v + 511) / 512 * 512; };
    unsigned short* hp = (unsigned short*)p; p += align512((size_t)N_NODES * HID_CH * 2);
    unsigned short* Wt = (unsigned short*)p; p += align512((size_t)IN_CH * HID_CH * 2);
    int* counts    = (int*)p;   p += align512((size_t)N_NODES * 4);
    float* dinv    = (float*)p; p += align512((size_t)N_NODES * 4);
    int* row_start = (int*)p;   p += align512((size_t)(N_NODES + 1) * 4);
    int* rank      = (int*)p;   p += align512((size_t)N_EDGES * 4);
    int* partials  = (int*)p;   p += align512(512 * 4);
    int* sorted    = (int*)p;   p += align512((size_t)N_EDGES * 4);

    hipMemsetAsync(counts, 0, (size_t)N_NODES * sizeof(int), stream);

    count_kernel<<<(N_EDGES + 255) / 256, 256, 0, stream>>>(ei + N_EDGES, counts, rank);
    scanA_kernel<<<SCAN_BLOCKS, 256, 0, stream>>>(counts, row_start, partials);
    scanB_kernel<<<1, 512, 0, stream>>>(partials);
    scanC_kernel<<<SCAN_BLOCKS, 256, 0, stream>>>(row_start, partials, counts, dinv);
    reorder_kernel<<<(N_EDGES + 255) / 256, 256, 0, stream>>>(ei, rank, row_start, sorted);

    wt_kernel<<<(IN_CH * HID_CH + 255) / 256, 256, 0, stream>>>(W, Wt);

    // 512 threads/block, 256 rows/block
    gemm_mfma_kernel<<<(N_NODES + 255) / 256, 512, 0, stream>>>(x, Wt, dinv, hp);

    long long gthreads = (long long)N_NODES * 64;
    gather_finalize_kernel<<<(int)((gthreads + 255) / 256), 256, 0, stream>>>(
        row_start, sorted, dinv, hp, bias, alpha, out);
}

// Round 3
// 296.597 us; speedup vs baseline: 1.3369x; 1.2021x over previous
//
#include <hip/hip_runtime.h>

#define N_NODES 100000
#define N_EDGES 1600000
#define IN_CH 256
#define HID_CH 128

// ---- two-level counting sort geometry ----
#define NBUCK 196            // ceil(100000 / 512) buckets of 512 nodes
#define NBLKC 400            // coarse blocks
#define EPB   4000           // edges per coarse block (400*4000 = 1.6M exactly)
#define SCAN2_LEN (NBUCK * NBLKC)              // 78400
#define SCAN2_BLOCKS ((SCAN2_LEN + 255) / 256) // 307

typedef __attribute__((ext_vector_type(8))) short short8;
typedef __attribute__((ext_vector_type(4))) float floatx4;

// fp32 -> bf16 round-to-nearest-even
static __device__ __forceinline__ unsigned short f2bf(float f) {
    unsigned int u = __float_as_uint(f);
    u += 0x7fffu + ((u >> 16) & 1u);
    return (unsigned short)(u >> 16);
}

// packed fp32x2 -> bf16x2 (RNE), S0 -> low16, S1 -> high16
static __device__ __forceinline__ unsigned cvt_pk_bf16(float lo, float hi) {
    unsigned r;
    asm("v_cvt_pk_bf16_f32 %0, %1, %2" : "=v"(r) : "v"(lo), "v"(hi));
    return r;
}

// ---------------- CSR build: atomic-free two-level counting sort ----------------

// Pass A: per-block LDS histogram of coarse buckets (dst>>9), transposed store.
__global__ void hist_kernel(const int* __restrict__ dst, int* __restrict__ histT) {
    __shared__ int h[NBUCK];
    int tid = threadIdx.x, blk = blockIdx.x;
    for (int b = tid; b < NBUCK; b += 256) h[b] = 0;
    __syncthreads();
    int base = blk * EPB;
    for (int e = base + tid; e < base + EPB; e += 256)
        atomicAdd(&h[dst[e] >> 9], 1);
    __syncthreads();
    for (int b = tid; b < NBUCK; b += 256) histT[b * NBLKC + blk] = h[b];
}

// Pass B: exclusive scan of the 78400-entry (bucket-major) matrix, in place.
__global__ void gscanA_kernel(int* __restrict__ data, int* __restrict__ partials) {
    __shared__ int ss[256];
    int tid = threadIdx.x;
    int i = blockIdx.x * 256 + tid;
    int v = (i < SCAN2_LEN) ? data[i] : 0;
    ss[tid] = v;
    __syncthreads();
    for (int off = 1; off < 256; off <<= 1) {
        int t = (tid >= off) ? ss[tid - off] : 0;
        __syncthreads();
        ss[tid] += t;
        __syncthreads();
    }
    if (i < SCAN2_LEN) data[i] = ss[tid] - v;
    if (tid == 255) partials[blockIdx.x] = ss[255];
}

__global__ void gscanB_kernel(int* __restrict__ partials) {
    __shared__ int ss[512];
    int tid = threadIdx.x;
    int v = (tid < SCAN2_BLOCKS) ? partials[tid] : 0;
    ss[tid] = v;
    __syncthreads();
    for (int off = 1; off < 512; off <<= 1) {
        int t = (tid >= off) ? ss[tid - off] : 0;
        __syncthreads();
        ss[tid] += t;
        __syncthreads();
    }
    if (tid < SCAN2_BLOCKS) partials[tid] = ss[tid] - v;
}

__global__ void gscanC_kernel(int* __restrict__ data, const int* __restrict__ partials) {
    int i = blockIdx.x * 256 + threadIdx.x;
    if (i < SCAN2_LEN) data[i] += partials[blockIdx.x];
}

// Pass C: scatter edges into coarse buckets. Per-(bucket,block) cursor ranges are
// disjoint by construction -> LDS cursors only, no global atomics.
// Packed record: src (17b) << 9 | (dst & 511).
__global__ void scatter_coarse_kernel(const int* __restrict__ ei,
                                      const int* __restrict__ offs,
                                      unsigned* __restrict__ bucketed) {
    __shared__ int cur[NBUCK];
    int tid = threadIdx.x, blk = blockIdx.x;
    for (int b = tid; b < NBUCK; b += 256) cur[b] = offs[b * NBLKC + blk];
    __syncthreads();
    int base = blk * EPB;
    for (int e = base + tid; e < base + EPB; e += 256) {
        int src = ei[e];
        int dst = ei[N_EDGES + e];
        int b = dst >> 9;
        int pos = atomicAdd(&cur[b], 1);
        bucketed[pos] = ((unsigned)src << 9) | (unsigned)(dst & 511);
    }
}

// Pass D: fine counting sort within each bucket (512 nodes), emit sorted srcs,
// row_start and dinv. One block of 512 threads per bucket.
__global__ void fine_kernel(const unsigned* __restrict__ bucketed,
                            const int* __restrict__ offs,
                            int* __restrict__ sorted,
                            int* __restrict__ row_start,
                            float* __restrict__ dinv) {
    __shared__ int bins[512];
    __shared__ int scanbuf[512];
    int b = blockIdx.x, tid = threadIdx.x;
    int bs = offs[b * NBLKC];
    int be = (b < NBUCK - 1) ? offs[(b + 1) * NBLKC] : N_EDGES;

    bins[tid] = 0;
    __syncthreads();
    for (int k = bs + tid; k < be; k += 512)
        atomicAdd(&bins[bucketed[k] & 511u], 1);
    __syncthreads();

    int c = bins[tid];
    scanbuf[tid] = c;
    __syncthreads();
    for (int off = 1; off < 512; off <<= 1) {
        int t = (tid >= off) ? scanbuf[tid - off] : 0;
        __syncthreads();
        scanbuf[tid] += t;
        __syncthreads();
    }
    int excl = scanbuf[tid] - c;

    int node = b * 512 + tid;
    if (node <= N_NODES) row_start[node] = bs + excl;
    if (node < N_NODES) dinv[node] = rsqrtf((float)(c + 1));   // +1 self loop

    bins[tid] = bs + excl;   // reuse as global cursor
    __syncthreads();
    for (int k = bs + tid; k < be; k += 512) {
        unsigned p = bucketed[k];
        int pos = atomicAdd(&bins[p & 511u], 1);
        sorted[pos] = (int)(p >> 9);
    }
}

// ---------------- W^T -> bf16 (one-time, 32K elems) ----------------

__global__ void wt_kernel(const float* __restrict__ W, unsigned short* __restrict__ Wt) {
    int i = blockIdx.x * blockDim.x + threadIdx.x;   // over IN_CH*HID_CH
    if (i >= IN_CH * HID_CH) return;
    int k = i >> 7;          // IN index
    int c = i & 127;         // HID index
    Wt[c * IN_CH + k] = f2bf(W[i]);
}

// ---------------- MFMA GEMM: hp = bf16( dinv[row] * (x @ W) ) ----------------
// 512 threads = 8 waves per block; block covers 256 rows (32 rows/wave).
// Wt staged once per block into LDS (64 KB, XOR-swizzled). A from global fp32 x
// with an explicit 2-deep register double-buffer.

__launch_bounds__(512)
__global__ void gemm_mfma_kernel(const float* __restrict__ x,
                                 const unsigned short* __restrict__ Wt,
                                 const float* __restrict__ dinv,
                                 unsigned short* __restrict__ hp) {
    __shared__ unsigned short Bs[IN_CH * HID_CH];   // 64 KB, swizzled

    int tid = threadIdx.x;

    // ---- stage Wt -> LDS, swizzled: byte ^= ((col&7)<<4) ----
    {
        const uint4* src = (const uint4*)Wt;
#pragma unroll
        for (int i = 0; i < 8; ++i) {
            int j = i * 512 + tid;                   // 16B chunk index, 4096 total
            unsigned lb = (unsigned)j * 16u;         // linear byte offset
            unsigned c7 = (lb >> 9) & 7u;            // col & 7 (row stride = 512B)
            unsigned db = lb ^ (c7 << 4);
            *(uint4*)((char*)Bs + db) = src[j];
        }
    }
    __syncthreads();

    int wave = tid >> 6;
    int lane = tid & 63;
    int row0 = blockIdx.x * 256 + wave * 32;
    if (row0 >= N_NODES) return;      // no barriers after this point

    int m = lane & 15;
    int q = lane >> 4;

    floatx4 acc[2][8];
#pragma unroll
    for (int i = 0; i < 2; ++i)
#pragma unroll
        for (int t = 0; t < 8; ++t) acc[i][t] = (floatx4){0.f, 0.f, 0.f, 0.f};

    // per-lane A rows (clamped; OOB rows masked at the store)
    int r0 = row0 + m;        if (r0 >= N_NODES) r0 = N_NODES - 1;
    int r1 = row0 + 16 + m;   if (r1 >= N_NODES) r1 = N_NODES - 1;
    const float* xp0 = &x[(size_t)r0 * IN_CH + q * 8];
    const float* xp1 = &x[(size_t)r1 * IN_CH + q * 8];

    float4 aA[4], aB[4];

#define LOADA(buf, kstep)                                          \
    do {                                                           \
        const float* p0_ = xp0 + (kstep) * 32;                     \
        const float* p1_ = xp1 + (kstep) * 32;                     \
        buf[0] = *(const float4*)(p0_);                            \
        buf[1] = *(const float4*)(p0_ + 4);                        \
        buf[2] = *(const float4*)(p1_);                            \
        buf[3] = *(const float4*)(p1_ + 4);                        \
    } while (0)

#define COMPUTE(buf, kstep)                                                     \
    do {                                                                        \
        union { short8 v; unsigned u[4]; } af0_, af1_;                          \
        af0_.u[0] = cvt_pk_bf16(buf[0].x, buf[0].y);                            \
        af0_.u[1] = cvt_pk_bf16(buf[0].z, buf[0].w);                            \
        af0_.u[2] = cvt_pk_bf16(buf[1].x, buf[1].y);                            \
        af0_.u[3] = cvt_pk_bf16(buf[1].z, buf[1].w);                            \
        af1_.u[0] = cvt_pk_bf16(buf[2].x, buf[2].y);                            \
        af1_.u[1] = cvt_pk_bf16(buf[2].z, buf[2].w);                            \
        af1_.u[2] = cvt_pk_bf16(buf[3].x, buf[3].y);                            \
        af1_.u[3] = cvt_pk_bf16(buf[3].z, buf[3].w);                            \
        int kb_ = ((kstep) * 32 + q * 8) * 2;                                   \
        _Pragma("unroll")                                                       \
        for (int t = 0; t < 8; ++t) {                                           \
            int c_ = t * 16 + m;                                                \
            unsigned db_ = (unsigned)(c_ * 512 + kb_) ^ ((unsigned)(c_ & 7) << 4); \
            short8 bf_ = *(const short8*)((const char*)Bs + db_);               \
            acc[0][t] = __builtin_amdgcn_mfma_f32_16x16x32_bf16(af0_.v, bf_, acc[0][t], 0, 0, 0); \
            acc[1][t] = __builtin_amdgcn_mfma_f32_16x16x32_bf16(af1_.v, bf_, acc[1][t], 0, 0, 0); \
        }                                                                       \
    } while (0)

    LOADA(aA, 0);
#pragma unroll 1
    for (int ks = 0; ks < 8; ks += 2) {
        LOADA(aB, ks + 1);
        COMPUTE(aA, ks);
        if (ks < 6) LOADA(aA, ks + 2);
        COMPUTE(aB, ks + 1);
    }

#undef LOADA
#undef COMPUTE

    // C/D layout: col = lane&15 (=m), row = q*4 + reg (within each 16-row tile)
#pragma unroll
    for (int tile = 0; tile < 2; ++tile) {
#pragma unroll
        for (int reg = 0; reg < 4; ++reg) {
            int grow = row0 + tile * 16 + q * 4 + reg;
            if (grow < N_NODES) {
                float di = dinv[grow];
                unsigned short* op = &hp[(size_t)grow * HID_CH + m];
#pragma unroll
                for (int tp = 0; tp < 4; ++tp) {
                    unsigned d = cvt_pk_bf16(acc[tile][2 * tp][reg] * di,
                                             acc[tile][2 * tp + 1][reg] * di);
                    op[(2 * tp) * 16]     = (unsigned short)(d & 0xffffu);
                    op[(2 * tp + 1) * 16] = (unsigned short)(d >> 16);
                }
            }
        }
    }
}

// ---------------- gather + finalize ----------------
// One wave per node, 4 edge-chains (parts) x 16 lanes x 8ch (uint4).
// Edge loop unrolled 4x per part with branchless masking: 16 independent
// hp-row loads in flight per wave.

static __device__ __forceinline__ void acc_bf16x8(float* acc, uint4 u, float w) {
    acc[0] += w * __uint_as_float(u.x << 16);
    acc[1] += w * __uint_as_float(u.x & 0xffff0000u);
    acc[2] += w * __uint_as_float(u.y << 16);
    acc[3] += w * __uint_as_float(u.y & 0xffff0000u);
    acc[4] += w * __uint_as_float(u.z << 16);
    acc[5] += w * __uint_as_float(u.z & 0xffff0000u);
    acc[6] += w * __uint_as_float(u.w << 16);
    acc[7] += w * __uint_as_float(u.w & 0xffff0000u);
}

__launch_bounds__(256)
__global__ void gather_finalize_kernel(const int* __restrict__ row_start,
                                       const int* __restrict__ sorted,
                                       const float* __restrict__ dinv,
                                       const unsigned short* __restrict__ hp,
                                       const float* __restrict__ bias,
                                       const float* __restrict__ alpha,
                                       float* __restrict__ out) {
    int node = (blockIdx.x * blockDim.x + threadIdx.x) >> 6;
    int lane = threadIdx.x & 63;
    if (node >= N_NODES) return;

    int beg = row_start[node];
    int end = row_start[node + 1];
    int part = lane >> 4;          // 0..3: which edge-chain
    int ch = (lane & 15) * 8;      // 8 channels per lane

    // independent loads issued before the edge loop (overlap its latency)
    float di = dinv[node];
    uint4 us = *(const uint4*)&hp[(size_t)node * HID_CH + ch];

    float acc[8];
#pragma unroll
    for (int i = 0; i < 8; ++i) acc[i] = 0.f;

    // 4x-unrolled masked edge loop: this part's edges are beg+part, +4, +8, ...
    for (int k = beg + part; k < end; k += 16) {
        int k1 = k + 4, k2 = k + 8, k3 = k + 12;
        int e1 = end - 1;
        int s0 = sorted[k];
        int s1 = sorted[k1 < end ? k1 : e1];
        int s2 = sorted[k2 < end ? k2 : e1];
        int s3 = sorted[k3 < end ? k3 : e1];
        uint4 u0 = *(const uint4*)&hp[(size_t)s0 * HID_CH + ch];
        uint4 u1 = *(const uint4*)&hp[(size_t)s1 * HID_CH + ch];
        uint4 u2 = *(const uint4*)&hp[(size_t)s2 * HID_CH + ch];
        uint4 u3 = *(const uint4*)&hp[(size_t)s3 * HID_CH + ch];
        float w1 = k1 < end ? 1.f : 0.f;
        float w2 = k2 < end ? 1.f : 0.f;
        float w3 = k3 < end ? 1.f : 0.f;
        acc_bf16x8(acc, u0, 1.f);
        acc_bf16x8(acc, u1, w1);
        acc_bf16x8(acc, u2, w2);
        acc_bf16x8(acc, u3, w3);
    }

    // combine the 4 edge-parts (lanes 0-15 / 16-31 / 32-47 / 48-63)
#pragma unroll
    for (int i = 0; i < 8; ++i) {
        acc[i] += __shfl_xor(acc[i], 16);
        acc[i] += __shfl_xor(acc[i], 32);
    }

    if (part == 0) {
        float sf[8];
        sf[0] = __uint_as_float(us.x << 16);
        sf[1] = __uint_as_float(us.x & 0xffff0000u);
        sf[2] = __uint_as_float(us.y << 16);
        sf[3] = __uint_as_float(us.y & 0xffff0000u);
        sf[4] = __uint_as_float(us.z << 16);
        sf[5] = __uint_as_float(us.z & 0xffff0000u);
        sf[6] = __uint_as_float(us.w << 16);
        sf[7] = __uint_as_float(us.w & 0xffff0000u);

        float4 b0 = *(const float4*)&bias[ch];
        float4 b1 = *(const float4*)&bias[ch + 4];
        float4 a0 = *(const float4*)&alpha[ch];
        float4 a1 = *(const float4*)&alpha[ch + 4];
        float bv[8] = {b0.x, b0.y, b0.z, b0.w, b1.x, b1.y, b1.z, b1.w};
        float av[8] = {a0.x, a0.y, a0.z, a0.w, a1.x, a1.y, a1.z, a1.w};

        float r[8];
#pragma unroll
        for (int i = 0; i < 8; ++i) {
            float v = di * (acc[i] + sf[i]) + bv[i];
            r[i] = v > 0.f ? v : av[i] * v;
        }
        float4 o0 = make_float4(r[0], r[1], r[2], r[3]);
        float4 o1 = make_float4(r[4], r[5], r[6], r[7]);
        *(float4*)&out[(size_t)node * HID_CH + ch] = o0;
        *(float4*)&out[(size_t)node * HID_CH + ch + 4] = o1;
    }
}

// ---------------- launch ----------------

extern "C" void kernel_launch(void* const* d_in, const int* in_sizes, int n_in,
                              void* d_out, int out_size, void* d_ws, size_t ws_size,
                              hipStream_t stream) {
    const float* x     = (const float*)d_in[0];
    const int*   ei    = (const int*)d_in[1];     // [2, E]: [0..E)=src, [E..2E)=dst
    const float* W     = (const float*)d_in[2];
    const float* bias  = (const float*)d_in[3];
    const float* alpha = (const float*)d_in[4];
    float* out = (float*)d_out;

    char* p = (char*)d_ws;
    auto align512 = [](size_t v) { return (v + 511) / 512 * 512; };
    unsigned short* hp = (unsigned short*)p; p += align512((size_t)N_NODES * HID_CH * 2);
    unsigned short* Wt = (unsigned short*)p; p += align512((size_t)IN_CH * HID_CH * 2);
    float* dinv    = (float*)p; p += align512((size_t)N_NODES * 4);
    int* row_start = (int*)p;   p += align512((size_t)(N_NODES + 1) * 4);
    int* histT     = (int*)p;   p += align512((size_t)SCAN2_LEN * 4);
    int* partials  = (int*)p;   p += align512(512 * 4);
    unsigned* bucketed = (unsigned*)p; p += align512((size_t)N_EDGES * 4);
    int* sorted    = (int*)p;   p += align512((size_t)N_EDGES * 4);

    // CSR build: atomic-free two-level counting sort
    hist_kernel<<<NBLKC, 256, 0, stream>>>(ei + N_EDGES, histT);
    gscanA_kernel<<<SCAN2_BLOCKS, 256, 0, stream>>>(histT, partials);
    gscanB_kernel<<<1, 512, 0, stream>>>(partials);
    gscanC_kernel<<<SCAN2_BLOCKS, 256, 0, stream>>>(histT, partials);
    scatter_coarse_kernel<<<NBLKC, 256, 0, stream>>>(ei, histT, bucketed);
    fine_kernel<<<NBUCK, 512, 0, stream>>>(bucketed, histT, sorted, row_start, dinv);

    wt_kernel<<<(IN_CH * HID_CH + 255) / 256, 256, 0, stream>>>(W, Wt);

    // 512 threads/block, 256 rows/block
    gemm_mfma_kernel<<<(N_NODES + 255) / 256, 512, 0, stream>>>(x, Wt, dinv, hp);

    long long gthreads = (long long)N_NODES * 64;
    gather_finalize_kernel<<<(int)((gthreads + 255) / 256), 256, 0, stream>>>(
        row_start, sorted, dinv, hp, bias, alpha, out);
}